// Round 1
// baseline (1109.474 us; speedup 1.0000x reference)
//
#include <hip/hip_runtime.h>
#include <hip/hip_bf16.h>

// GCN x3 + FC on a fixed random graph.
// Strategy:
//   1. Build in-edge CSR once per call (count -> scan -> fill), deg includes no
//      self loop; dinv = rsqrt(deg+1).
//   2. Per layer: pull-based aggregation in the INPUT feature dim (8/16/32),
//      then dense per-node transform (+bias, relu).
//   3. Last transform fused with the final FC (keeps t[64] in registers).

#define SCAN_BLOCK 256
#define SCAN_ELEMS 4   // elements per thread in scan kernels -> 1024/block

__global__ void count_kernel(const int* __restrict__ dst, int* __restrict__ deg, int E) {
    int e = blockIdx.x * blockDim.x + threadIdx.x;
    if (e < E) atomicAdd(&deg[dst[e]], 1);
}

// Per-block exclusive scan over 1024 deg entries; also emits dinv = rsqrt(deg+1).
__global__ void scan1_kernel(const int* __restrict__ deg, int* __restrict__ off,
                             int* __restrict__ bsum, float* __restrict__ dinv, int n) {
    __shared__ int sh[SCAN_BLOCK];
    int tid = threadIdx.x;
    int base = (blockIdx.x * SCAN_BLOCK + tid) * SCAN_ELEMS;
    int d[SCAN_ELEMS];
#pragma unroll
    for (int i = 0; i < SCAN_ELEMS; i++) {
        d[i] = deg[base + i];
        dinv[base + i] = rsqrtf((float)(d[i] + 1));
    }
    int s = d[0] + d[1] + d[2] + d[3];
    sh[tid] = s;
    __syncthreads();
    for (int o = 1; o < SCAN_BLOCK; o <<= 1) {
        int v = (tid >= o) ? sh[tid - o] : 0;
        __syncthreads();
        sh[tid] += v;
        __syncthreads();
    }
    int excl = sh[tid] - s;
    if (tid == SCAN_BLOCK - 1) bsum[blockIdx.x] = sh[SCAN_BLOCK - 1];
    int run = excl;
#pragma unroll
    for (int i = 0; i < SCAN_ELEMS; i++) { off[base + i] = run; run += d[i]; }
}

// Exclusive scan of the (<=256) block sums, single block.
__global__ void scan2_kernel(int* __restrict__ bsum, int nblocks) {
    __shared__ int sh[SCAN_BLOCK];
    int tid = threadIdx.x;
    int s = (tid < nblocks) ? bsum[tid] : 0;
    sh[tid] = s;
    __syncthreads();
    for (int o = 1; o < SCAN_BLOCK; o <<= 1) {
        int v = (tid >= o) ? sh[tid - o] : 0;
        __syncthreads();
        sh[tid] += v;
        __syncthreads();
    }
    if (tid < nblocks) bsum[tid] = sh[tid] - s;
}

// Add block offsets; also initialize the fill cursors.
__global__ void scan3_kernel(int* __restrict__ off, const int* __restrict__ bsum,
                             int* __restrict__ cursor) {
    int add = bsum[blockIdx.x];
    int base = (blockIdx.x * SCAN_BLOCK + threadIdx.x) * SCAN_ELEMS;
#pragma unroll
    for (int i = 0; i < SCAN_ELEMS; i++) {
        int v = off[base + i] + add;
        off[base + i] = v;
        cursor[base + i] = v;
    }
}

__global__ void fill_kernel(const int* __restrict__ src, const int* __restrict__ dst,
                            int* __restrict__ cursor, int* __restrict__ adj, int E) {
    int e = blockIdx.x * blockDim.x + threadIdx.x;
    if (e < E) {
        int d = dst[e];
        int p = atomicAdd(&cursor[d], 1);
        adj[p] = src[e];
    }
}

// Pull aggregation: out[v] = dinv[v] * (sum_{s in in(v)} dinv[s]*x[s] + dinv[v]*x[v])
// C = number of float4 chunks per feature row (F/4). C lanes cooperate per node.
template <int C>
__global__ void agg_kernel(const float* __restrict__ x, const int* __restrict__ off,
                           const int* __restrict__ adj, const float* __restrict__ dinv,
                           float* __restrict__ out, int n, int E) {
    int t = blockIdx.x * blockDim.x + threadIdx.x;
    int v = t / C;
    int c = t % C;
    if (v >= n) return;
    const float4* x4 = (const float4*)x;
    float wv = dinv[v];
    float4 xv = x4[(size_t)v * C + c];
    float4 acc;
    acc.x = wv * xv.x; acc.y = wv * xv.y; acc.z = wv * xv.z; acc.w = wv * xv.w;
    int beg = off[v];
    int end = (v == n - 1) ? E : off[v + 1];
    for (int e = beg; e < end; e++) {
        int s = adj[e];
        float ws = dinv[s];
        float4 xs = x4[(size_t)s * C + c];
        acc.x += ws * xs.x; acc.y += ws * xs.y; acc.z += ws * xs.z; acc.w += ws * xs.w;
    }
    float4 o;
    o.x = acc.x * wv; o.y = acc.y * wv; o.z = acc.z * wv; o.w = acc.w * wv;
    ((float4*)out)[(size_t)v * C + c] = o;
}

// Dense per-node transform: out[v] = act(in[v] @ W + b). W: [FIN, FOUT] row-major.
template <int FIN, int FOUT, bool RELU>
__global__ void transform_kernel(const float* __restrict__ in, const float* __restrict__ W,
                                 const float* __restrict__ b, float* __restrict__ out, int n) {
    __shared__ float Ws[FIN * FOUT];
    __shared__ float bs[FOUT];
    for (int i = threadIdx.x; i < FIN * FOUT; i += blockDim.x) Ws[i] = W[i];
    if (threadIdx.x < FOUT) bs[threadIdx.x] = b[threadIdx.x];
    __syncthreads();
    int v = blockIdx.x * blockDim.x + threadIdx.x;
    if (v >= n) return;
    float a[FIN];
    const float4* in4 = (const float4*)(in + (size_t)v * FIN);
#pragma unroll
    for (int k = 0; k < FIN / 4; k++) {
        float4 t = in4[k];
        a[4 * k] = t.x; a[4 * k + 1] = t.y; a[4 * k + 2] = t.z; a[4 * k + 3] = t.w;
    }
    float4* out4 = (float4*)(out + (size_t)v * FOUT);
#pragma unroll
    for (int j = 0; j < FOUT; j += 4) {
        float acc0 = bs[j], acc1 = bs[j + 1], acc2 = bs[j + 2], acc3 = bs[j + 3];
#pragma unroll
        for (int k = 0; k < FIN; k++) {
            float xv = a[k];
            acc0 += xv * Ws[k * FOUT + j];
            acc1 += xv * Ws[k * FOUT + j + 1];
            acc2 += xv * Ws[k * FOUT + j + 2];
            acc3 += xv * Ws[k * FOUT + j + 3];
        }
        float4 o;
        if (RELU) {
            o.x = fmaxf(acc0, 0.f); o.y = fmaxf(acc1, 0.f);
            o.z = fmaxf(acc2, 0.f); o.w = fmaxf(acc3, 0.f);
        } else {
            o.x = acc0; o.y = acc1; o.z = acc2; o.w = acc3;
        }
        out4[j / 4] = o;
    }
}

// Fused: out[v] = relu(a3[v] @ W3 + b3) @ Wfc + bfc  (32 -> 64 -> 64)
__global__ void t3fc_kernel(const float* __restrict__ in,
                            const float* __restrict__ W3, const float* __restrict__ b3,
                            const float* __restrict__ Wf, const float* __restrict__ bf,
                            float* __restrict__ out, int n) {
    __shared__ float W3s[32 * 64];
    __shared__ float Wfs[64 * 64];
    __shared__ float b3s[64];
    __shared__ float bfs[64];
    for (int i = threadIdx.x; i < 32 * 64; i += blockDim.x) W3s[i] = W3[i];
    for (int i = threadIdx.x; i < 64 * 64; i += blockDim.x) Wfs[i] = Wf[i];
    if (threadIdx.x < 64) { b3s[threadIdx.x] = b3[threadIdx.x]; bfs[threadIdx.x] = bf[threadIdx.x]; }
    __syncthreads();
    int v = blockIdx.x * blockDim.x + threadIdx.x;
    if (v >= n) return;
    float a[32];
    const float4* in4 = (const float4*)(in + (size_t)v * 32);
#pragma unroll
    for (int k = 0; k < 8; k++) {
        float4 t = in4[k];
        a[4 * k] = t.x; a[4 * k + 1] = t.y; a[4 * k + 2] = t.z; a[4 * k + 3] = t.w;
    }
    float tt[64];
#pragma unroll
    for (int j = 0; j < 64; j++) {
        float acc = b3s[j];
#pragma unroll
        for (int k = 0; k < 32; k++) acc += a[k] * W3s[k * 64 + j];
        tt[j] = fmaxf(acc, 0.f);
    }
    float4* out4 = (float4*)(out + (size_t)v * 64);
#pragma unroll
    for (int j = 0; j < 64; j += 4) {
        float acc0 = bfs[j], acc1 = bfs[j + 1], acc2 = bfs[j + 2], acc3 = bfs[j + 3];
#pragma unroll
        for (int k = 0; k < 64; k++) {
            float tv = tt[k];
            acc0 += tv * Wfs[k * 64 + j];
            acc1 += tv * Wfs[k * 64 + j + 1];
            acc2 += tv * Wfs[k * 64 + j + 2];
            acc3 += tv * Wfs[k * 64 + j + 3];
        }
        float4 o;
        o.x = acc0; o.y = acc1; o.z = acc2; o.w = acc3;
        out4[j / 4] = o;
    }
}

extern "C" void kernel_launch(void* const* d_in, const int* in_sizes, int n_in,
                              void* d_out, int out_size, void* d_ws, size_t ws_size,
                              hipStream_t stream) {
    const float* x  = (const float*)d_in[0];
    const float* W1 = (const float*)d_in[1];
    const float* b1 = (const float*)d_in[2];
    const float* W2 = (const float*)d_in[3];
    const float* b2 = (const float*)d_in[4];
    const float* W3 = (const float*)d_in[5];
    const float* b3 = (const float*)d_in[6];
    const float* Wf = (const float*)d_in[7];
    const float* bf = (const float*)d_in[8];
    const int*   ei = (const int*)d_in[9];

    const int N = in_sizes[0] / 8;   // 262144
    const int E = in_sizes[9] / 2;   // 2097152
    const int* srcv = ei;
    const int* dstv = ei + E;

    // Workspace layout
    char* p = (char*)d_ws;
    int*   off    = (int*)p;            p += (size_t)N * 4;
    int*   deg    = (int*)p;            p += (size_t)N * 4;
    int*   cursor = (int*)p;            p += (size_t)N * 4;
    float* dinv   = (float*)p;          p += (size_t)N * 4;
    int*   bsum   = (int*)p;            p += 1024;            // up to 256 block sums
    int*   adj    = (int*)p;            p += (size_t)E * 4;
    float* bufA   = (float*)p;          p += (size_t)N * 32 * 4;
    float* bufB   = (float*)p;          p += (size_t)N * 32 * 4;

    hipMemsetAsync(deg, 0, (size_t)N * 4, stream);

    int eb = (E + 255) / 256;
    count_kernel<<<eb, 256, 0, stream>>>(dstv, deg, E);

    int sb = N / (SCAN_BLOCK * SCAN_ELEMS);  // 256 blocks at N=262144
    scan1_kernel<<<sb, SCAN_BLOCK, 0, stream>>>(deg, off, bsum, dinv, N);
    scan2_kernel<<<1, SCAN_BLOCK, 0, stream>>>(bsum, sb);
    scan3_kernel<<<sb, SCAN_BLOCK, 0, stream>>>(off, bsum, cursor);
    fill_kernel<<<eb, 256, 0, stream>>>(srcv, dstv, cursor, adj, E);

    // Layer 1: aggregate x [N,8] -> bufA, transform 8->16 -> bufB
    agg_kernel<2><<<(N * 2 + 255) / 256, 256, 0, stream>>>(x, off, adj, dinv, bufA, N, E);
    transform_kernel<8, 16, true><<<(N + 255) / 256, 256, 0, stream>>>(bufA, W1, b1, bufB, N);

    // Layer 2: aggregate h1 [N,16] -> bufA, transform 16->32 -> bufB
    agg_kernel<4><<<(N * 4 + 255) / 256, 256, 0, stream>>>(bufB, off, adj, dinv, bufA, N, E);
    transform_kernel<16, 32, true><<<(N + 255) / 256, 256, 0, stream>>>(bufA, W2, b2, bufB, N);

    // Layer 3: aggregate h2 [N,32] -> bufA, fused transform 32->64 + FC 64->64 -> out
    agg_kernel<8><<<(N * 8 + 255) / 256, 256, 0, stream>>>(bufB, off, adj, dinv, bufA, N, E);
    t3fc_kernel<<<(N + 255) / 256, 256, 0, stream>>>(bufA, W3, b3, Wf, bf, (float*)d_out, N);
}